// Round 9
// baseline (292.008 us; speedup 1.0000x reference)
//
#include <hip/hip_runtime.h>
#include <math.h>

#define Nn 50000
#define Ee 800000
#define Cc 96

#define SCAN_B 256
#define SCAN_NB ((Nn + SCAN_B - 1) / SCAN_B)   // 196

typedef __attribute__((ext_vector_type(8))) __bf16 bf16x8;
typedef __attribute__((ext_vector_type(4))) float f32x4;

// split fp32 into hi/lo bf16 (truncation; lo captures next 8 mantissa bits)
__device__ inline void split_bf16(float v, unsigned short& hi, unsigned short& lo) {
    unsigned u = __float_as_uint(v);
    hi = (unsigned short)(u >> 16);
    float rem = v - __uint_as_float(((unsigned)hi) << 16);
    lo = (unsigned short)(__float_as_uint(rem) >> 16);
}

// ============ prep: sort linear0 hidden units by relu threshold ============
// e(ea) = relu(ea*w0 + b0) @ W_l1 + b_l1 is piecewise-linear in scalar ea.
// Unit c active iff ea > t_c (w0>0) or ea < t_c (w0<0), t_c = -b0/w0.
// With thresholds sorted, k = #{t_i < ea} in [0,96] determines the active set.
__global__ void prep_sort_kernel(const float* __restrict__ Wl0, const float* __restrict__ bl0,
                                 float* __restrict__ st, float* __restrict__ sw,
                                 float* __restrict__ sb, int* __restrict__ so) {
    __shared__ float t_s[Cc];
    int c = threadIdx.x;
    float w = 0.f, b = 0.f, t = 0.f;
    if (c < Cc) {
        w = Wl0[c]; b = bl0[c];
        t = (w != 0.0f) ? (-b / w) : INFINITY;
        t_s[c] = t;
    }
    __syncthreads();
    if (c < Cc) {
        int r = 0;
        for (int j = 0; j < Cc; ++j) {
            float tj = t_s[j];
            r += (tj < t || (tj == t && j < c)) ? 1 : 0;  // stable rank sort
        }
        st[r] = t; sw[r] = w; sb[r] = b; so[r] = c;
    }
}

// Table in gather-friendly layout: tab[k][j] = float4{A[2j], B[2j], A[2j+1], B[2j+1]},
// j = 0..47 channel pairs, k = 0..96 activation patterns. 75 KB.
__global__ void build_table_kernel(const float* __restrict__ sw, const float* __restrict__ sb,
                                   const int* __restrict__ so, const float* __restrict__ Wl1,
                                   const float* __restrict__ bl1,
                                   float* __restrict__ tabf) {
    int k = blockIdx.x;          // 0..96
    int c2 = threadIdx.x;
    if (c2 >= Cc) return;
    float a = 0.f, bacc = bl1[c2];
    for (int i = 0; i < Cc; ++i) {
        float w = sw[i], b = sb[i];
        float wv = Wl1[so[i] * Cc + c2];
        bool act = (w > 0.f) ? (i < k) : ((w < 0.f) ? (i >= k) : (b > 0.f));
        if (act) { a = fmaf(w, wv, a); bacc = fmaf(b, wv, bacc); }
    }
    int base = k * (2 * Cc) + (c2 >> 1) * 4 + ((c2 & 1) << 1);
    tabf[base] = a;
    tabf[base + 1] = bacc;
}

// ============ CSR build (by dst), reused for both convs ============
// NOTE: harness delivers integer inputs as int32 — edge_index is const int*.
__global__ void hist_kernel(const int* __restrict__ ei, int* __restrict__ counts) {
    int e = blockIdx.x * blockDim.x + threadIdx.x;
    if (e >= Ee) return;
    int d = ei[Ee + e];
    if ((unsigned)d >= (unsigned)Nn) return;   // defensive: drop bad edges
    atomicAdd(&counts[d], 1);
}

// ---- 3-phase multi-block exclusive scan over counts[Nn] ----
__global__ __launch_bounds__(SCAN_B) void scan_sum_kernel(const int* __restrict__ counts,
                                                          int* __restrict__ bsum) {
    int i = blockIdx.x * SCAN_B + threadIdx.x;
    int v = (i < Nn) ? counts[i] : 0;
    for (int o = 32; o > 0; o >>= 1) v += __shfl_down(v, o, 64);
    __shared__ int ws[SCAN_B / 64];
    if ((threadIdx.x & 63) == 0) ws[threadIdx.x >> 6] = v;
    __syncthreads();
    if (threadIdx.x == 0) {
        int s = 0;
        for (int k = 0; k < SCAN_B / 64; ++k) s += ws[k];
        bsum[blockIdx.x] = s;
    }
}

__global__ __launch_bounds__(256) void scan_bsum_kernel(const int* __restrict__ bsum,
                                                        int* __restrict__ boff,
                                                        int* __restrict__ rowptr) {
    __shared__ int lds[256];
    int t = threadIdx.x;
    int v = (t < SCAN_NB) ? bsum[t] : 0;
    lds[t] = v;
    __syncthreads();
    for (int o = 1; o < 256; o <<= 1) {
        int u = (t >= o) ? lds[t - o] : 0;
        __syncthreads();
        lds[t] += u;
        __syncthreads();
    }
    if (t < SCAN_NB) boff[t] = lds[t] - v;
    if (t == 255) rowptr[Nn] = lds[255];
}

__global__ __launch_bounds__(SCAN_B) void scan_blocks_kernel(const int* __restrict__ counts,
                                                             const int* __restrict__ boff,
                                                             int* __restrict__ rowptr,
                                                             int* __restrict__ cursor) {
    __shared__ int lds[SCAN_B];
    int i = blockIdx.x * SCAN_B + threadIdx.x;
    int t = threadIdx.x;
    int v = (i < Nn) ? counts[i] : 0;
    lds[t] = v;
    __syncthreads();
    for (int o = 1; o < SCAN_B; o <<= 1) {
        int u = (t >= o) ? lds[t - o] : 0;
        __syncthreads();
        lds[t] += u;
        __syncthreads();
    }
    if (i < Nn) {
        int excl = lds[t] - v + boff[blockIdx.x];
        rowptr[i] = excl;
        cursor[i] = excl;
    }
}

// fill CSR: per edge store int2{ src | k<<20, bits(ea) }; k found once here.
__global__ void fill_kernel(const int* __restrict__ ei, const float* __restrict__ eattr,
                            const float* __restrict__ st, int* __restrict__ cursor,
                            int2* __restrict__ me) {
    __shared__ float ts[Cc];
    if (threadIdx.x < Cc) ts[threadIdx.x] = st[threadIdx.x];
    __syncthreads();
    int e = blockIdx.x * blockDim.x + threadIdx.x;
    if (e >= Ee) return;
    int s = ei[e];
    int d = ei[Ee + e];
    if ((unsigned)s >= (unsigned)Nn || (unsigned)d >= (unsigned)Nn) return;  // defensive
    float ea = eattr[e];
    int lo = 0, hi = Cc;          // k = count of thresholds < ea
    while (lo < hi) {
        int m = (lo + hi) >> 1;
        if (ts[m] < ea) lo = m + 1; else hi = m;
    }
    int pos = atomicAdd(&cursor[d], 1);
    if ((unsigned)pos >= (unsigned)Ee) return;  // defensive
    me[pos] = make_int2(s | (lo << 20), __float_as_int(ea));
}

// ============ aggregation: out[n] = feat[n] + sum_in relu(feat[src] + e) ============
// Persistent blocks: 1024 thr (16 waves), full 75 KB table staged in LDS once,
// then grid-stride wave-per-node. Lanes 0..47 own a channel PAIR (float2).
// Edge loop 8-deep unrolled: 8 meta + 8 feat gathers + 8 ds_reads issued before
// any use -> 8 gather chains in flight per wave (latency-bound regime).
#define AGG_NB 512
__global__ __launch_bounds__(1024) void aggregate_kernel(
        const float* __restrict__ feat, const int* __restrict__ rowptr,
        const int2* __restrict__ me, const float4* __restrict__ tab,
        float* __restrict__ out) {
    __shared__ float4 tl[(Cc + 1) * 48];   // 97*48*16 = 74496 B
    int tid = threadIdx.x;
    for (int i = tid; i < (Cc + 1) * 48; i += 1024) tl[i] = tab[i];
    __syncthreads();
    int wave = tid >> 6, lane = tid & 63;
    if (lane >= 48) return;               // no further syncs below
    int j = lane;                          // channel pair index, 0..47
    const float2* f2 = (const float2*)feat;
    for (int node = blockIdx.x * 16 + wave; node < Nn; node += AGG_NB * 16) {
        float2 acc = f2[(size_t)node * 48 + j];
        int s = rowptr[node], e = rowptr[node + 1];
        int p = s;
        for (; p + 8 <= e; p += 8) {
            int2 m0 = me[p],     m1 = me[p + 1], m2 = me[p + 2], m3 = me[p + 3];
            int2 m4 = me[p + 4], m5 = me[p + 5], m6 = me[p + 6], m7 = me[p + 7];
            float2 f0 = f2[(size_t)(m0.x & 0xFFFFF) * 48 + j];
            float2 f1 = f2[(size_t)(m1.x & 0xFFFFF) * 48 + j];
            float2 fb2 = f2[(size_t)(m2.x & 0xFFFFF) * 48 + j];
            float2 f3 = f2[(size_t)(m3.x & 0xFFFFF) * 48 + j];
            float2 f4 = f2[(size_t)(m4.x & 0xFFFFF) * 48 + j];
            float2 f5 = f2[(size_t)(m5.x & 0xFFFFF) * 48 + j];
            float2 f6 = f2[(size_t)(m6.x & 0xFFFFF) * 48 + j];
            float2 f7 = f2[(size_t)(m7.x & 0xFFFFF) * 48 + j];
            float4 t0 = tl[(m0.x >> 20) * 48 + j];
            float4 t1 = tl[(m1.x >> 20) * 48 + j];
            float4 t2 = tl[(m2.x >> 20) * 48 + j];
            float4 t3 = tl[(m3.x >> 20) * 48 + j];
            float4 t4 = tl[(m4.x >> 20) * 48 + j];
            float4 t5 = tl[(m5.x >> 20) * 48 + j];
            float4 t6 = tl[(m6.x >> 20) * 48 + j];
            float4 t7 = tl[(m7.x >> 20) * 48 + j];
            float ea0 = __int_as_float(m0.y), ea1 = __int_as_float(m1.y);
            float ea2 = __int_as_float(m2.y), ea3 = __int_as_float(m3.y);
            float ea4 = __int_as_float(m4.y), ea5 = __int_as_float(m5.y);
            float ea6 = __int_as_float(m6.y), ea7 = __int_as_float(m7.y);
            acc.x += fmaxf(f0.x + fmaf(ea0, t0.x, t0.y), 0.f);
            acc.y += fmaxf(f0.y + fmaf(ea0, t0.z, t0.w), 0.f);
            acc.x += fmaxf(f1.x + fmaf(ea1, t1.x, t1.y), 0.f);
            acc.y += fmaxf(f1.y + fmaf(ea1, t1.z, t1.w), 0.f);
            acc.x += fmaxf(fb2.x + fmaf(ea2, t2.x, t2.y), 0.f);
            acc.y += fmaxf(fb2.y + fmaf(ea2, t2.z, t2.w), 0.f);
            acc.x += fmaxf(f3.x + fmaf(ea3, t3.x, t3.y), 0.f);
            acc.y += fmaxf(f3.y + fmaf(ea3, t3.z, t3.w), 0.f);
            acc.x += fmaxf(f4.x + fmaf(ea4, t4.x, t4.y), 0.f);
            acc.y += fmaxf(f4.y + fmaf(ea4, t4.z, t4.w), 0.f);
            acc.x += fmaxf(f5.x + fmaf(ea5, t5.x, t5.y), 0.f);
            acc.y += fmaxf(f5.y + fmaf(ea5, t5.z, t5.w), 0.f);
            acc.x += fmaxf(f6.x + fmaf(ea6, t6.x, t6.y), 0.f);
            acc.y += fmaxf(f6.y + fmaf(ea6, t6.z, t6.w), 0.f);
            acc.x += fmaxf(f7.x + fmaf(ea7, t7.x, t7.y), 0.f);
            acc.y += fmaxf(f7.y + fmaf(ea7, t7.z, t7.w), 0.f);
        }
        for (; p + 4 <= e; p += 4) {
            int2 m0 = me[p], m1 = me[p + 1], m2 = me[p + 2], m3 = me[p + 3];
            float2 f0 = f2[(size_t)(m0.x & 0xFFFFF) * 48 + j];
            float2 f1 = f2[(size_t)(m1.x & 0xFFFFF) * 48 + j];
            float2 fb2 = f2[(size_t)(m2.x & 0xFFFFF) * 48 + j];
            float2 f3 = f2[(size_t)(m3.x & 0xFFFFF) * 48 + j];
            float4 t0 = tl[(m0.x >> 20) * 48 + j];
            float4 t1 = tl[(m1.x >> 20) * 48 + j];
            float4 t2 = tl[(m2.x >> 20) * 48 + j];
            float4 t3 = tl[(m3.x >> 20) * 48 + j];
            float ea0 = __int_as_float(m0.y), ea1 = __int_as_float(m1.y);
            float ea2 = __int_as_float(m2.y), ea3 = __int_as_float(m3.y);
            acc.x += fmaxf(f0.x + fmaf(ea0, t0.x, t0.y), 0.f);
            acc.y += fmaxf(f0.y + fmaf(ea0, t0.z, t0.w), 0.f);
            acc.x += fmaxf(f1.x + fmaf(ea1, t1.x, t1.y), 0.f);
            acc.y += fmaxf(f1.y + fmaf(ea1, t1.z, t1.w), 0.f);
            acc.x += fmaxf(fb2.x + fmaf(ea2, t2.x, t2.y), 0.f);
            acc.y += fmaxf(fb2.y + fmaf(ea2, t2.z, t2.w), 0.f);
            acc.x += fmaxf(f3.x + fmaf(ea3, t3.x, t3.y), 0.f);
            acc.y += fmaxf(f3.y + fmaf(ea3, t3.z, t3.w), 0.f);
        }
        for (; p < e; ++p) {
            int2 m0 = me[p];
            float2 f0 = f2[(size_t)(m0.x & 0xFFFFF) * 48 + j];
            float4 t0 = tl[(m0.x >> 20) * 48 + j];
            float ea0 = __int_as_float(m0.y);
            acc.x += fmaxf(f0.x + fmaf(ea0, t0.x, t0.y), 0.f);
            acc.y += fmaxf(f0.y + fmaf(ea0, t0.z, t0.w), 0.f);
        }
        ((float2*)out)[(size_t)node * 48 + j] = acc;
    }
}

// ============ fused 2-layer node MLP via bf16x3 MFMA ============
// out = relu(relu(in@W1+b1)@W2+b2), fp32 emulated as hi/lo bf16 (3 MFMA/product).
// Block: 256 thr = 4 waves, 64 rows; wave w owns rows w*16..w*16+15, all 96 cols.
// LDS: x hi/lo [64][104] bf16 + W^T hi/lo [96][104] bf16. IN-PLACE SAFE.
#define MLP_PAD 104
__global__ __launch_bounds__(256) void mlp2_kernel(
        const float* __restrict__ in, const float* __restrict__ W1g, const float* __restrict__ b1g,
        const float* __restrict__ W2g, const float* __restrict__ b2g, float* __restrict__ out) {
    __shared__ unsigned short xh[64 * MLP_PAD], xl[64 * MLP_PAD];
    __shared__ unsigned short wth[96 * MLP_PAD], wtl[96 * MLP_PAD];
    __shared__ float bb1[Cc], bb2[Cc];
    int tid = threadIdx.x;
    int row0 = blockIdx.x * 64;

    for (int t = 0; t < 24; ++t) {
        int idx = tid + t * 256;                 // 0..6143
        int r = idx / Cc, c = idx - r * Cc;
        int gr = row0 + r;
        float v = (gr < Nn) ? in[(size_t)gr * Cc + c] : 0.f;
        unsigned short hi, lo;
        split_bf16(v, hi, lo);
        xh[r * MLP_PAD + c] = hi; xl[r * MLP_PAD + c] = lo;
    }
    for (int t = 0; t < 36; ++t) {
        int idx = tid + t * 256;                 // 0..9215
        int k = idx / Cc, n = idx - k * Cc;
        unsigned short hi, lo;
        split_bf16(W1g[idx], hi, lo);
        wth[n * MLP_PAD + k] = hi; wtl[n * MLP_PAD + k] = lo;
    }
    if (tid < Cc) { bb1[tid] = b1g[tid]; bb2[tid] = b2g[tid]; }
    __syncthreads();

    int lane = tid & 63, w = tid >> 6;
    int li = lane & 15, lg = lane >> 4;          // li: m/n idx; lg: k-group
    int arow = w * 16 + li;                      // A row (A: row=lane&15, k=8*lg+e)

    f32x4 acc[6];
    // ---- layer 1 ----
    for (int nt = 0; nt < 6; ++nt) {
        float bv = bb1[nt * 16 + li];
        acc[nt] = (f32x4){bv, bv, bv, bv};
    }
    for (int k0 = 0; k0 < Cc; k0 += 32) {
        int ko = k0 + lg * 8;
        bf16x8 ah = *(const bf16x8*)&xh[arow * MLP_PAD + ko];
        bf16x8 al = *(const bf16x8*)&xl[arow * MLP_PAD + ko];
        for (int nt = 0; nt < 6; ++nt) {
            bf16x8 bh = *(const bf16x8*)&wth[(nt * 16 + li) * MLP_PAD + ko];
            bf16x8 bl = *(const bf16x8*)&wtl[(nt * 16 + li) * MLP_PAD + ko];
            acc[nt] = __builtin_amdgcn_mfma_f32_16x16x32_bf16(ah, bh, acc[nt], 0, 0, 0);
            acc[nt] = __builtin_amdgcn_mfma_f32_16x16x32_bf16(ah, bl, acc[nt], 0, 0, 0);
            acc[nt] = __builtin_amdgcn_mfma_f32_16x16x32_bf16(al, bh, acc[nt], 0, 0, 0);
        }
    }
    __syncthreads();   // all waves done reading wt & x
    for (int nt = 0; nt < 6; ++nt) {
        for (int r = 0; r < 4; ++r) {
            float v = fmaxf(acc[nt][r], 0.f);
            int row = w * 16 + lg * 4 + r;
            int col = nt * 16 + li;
            unsigned short hi, lo;
            split_bf16(v, hi, lo);
            xh[row * MLP_PAD + col] = hi; xl[row * MLP_PAD + col] = lo;
        }
    }
    for (int t = 0; t < 36; ++t) {
        int idx = tid + t * 256;
        int k = idx / Cc, n = idx - k * Cc;
        unsigned short hi, lo;
        split_bf16(W2g[idx], hi, lo);
        wth[n * MLP_PAD + k] = hi; wtl[n * MLP_PAD + k] = lo;
    }
    __syncthreads();

    // ---- layer 2 ----
    for (int nt = 0; nt < 6; ++nt) {
        float bv = bb2[nt * 16 + li];
        acc[nt] = (f32x4){bv, bv, bv, bv};
    }
    for (int k0 = 0; k0 < Cc; k0 += 32) {
        int ko = k0 + lg * 8;
        bf16x8 ah = *(const bf16x8*)&xh[arow * MLP_PAD + ko];
        bf16x8 al = *(const bf16x8*)&xl[arow * MLP_PAD + ko];
        for (int nt = 0; nt < 6; ++nt) {
            bf16x8 bh = *(const bf16x8*)&wth[(nt * 16 + li) * MLP_PAD + ko];
            bf16x8 bl = *(const bf16x8*)&wtl[(nt * 16 + li) * MLP_PAD + ko];
            acc[nt] = __builtin_amdgcn_mfma_f32_16x16x32_bf16(ah, bh, acc[nt], 0, 0, 0);
            acc[nt] = __builtin_amdgcn_mfma_f32_16x16x32_bf16(ah, bl, acc[nt], 0, 0, 0);
            acc[nt] = __builtin_amdgcn_mfma_f32_16x16x32_bf16(al, bh, acc[nt], 0, 0, 0);
        }
    }
    for (int nt = 0; nt < 6; ++nt) {
        for (int r = 0; r < 4; ++r) {
            int grow = row0 + w * 16 + lg * 4 + r;
            if (grow < Nn)
                out[(size_t)grow * Cc + nt * 16 + li] = fmaxf(acc[nt][r], 0.f);
        }
    }
}

extern "C" void kernel_launch(void* const* d_in, const int* in_sizes, int n_in,
                              void* d_out, int out_size, void* d_ws, size_t ws_size,
                              hipStream_t stream) {
    const float* x     = (const float*)d_in[0];
    const int*   ei    = (const int*)d_in[1];     // int64 in ref -> int32 from harness
    const float* eattr = (const float*)d_in[2];
    const float* Wl0   = (const float*)d_in[3];
    const float* bl0   = (const float*)d_in[4];
    const float* Wl1   = (const float*)d_in[5];
    const float* bl1   = (const float*)d_in[6];
    const float* W00   = (const float*)d_in[7];
    const float* b00   = (const float*)d_in[8];
    const float* W01   = (const float*)d_in[9];
    const float* b01   = (const float*)d_in[10];
    const float* W10   = (const float*)d_in[11];
    const float* b10   = (const float*)d_in[12];
    const float* W11   = (const float*)d_in[13];
    const float* b11   = (const float*)d_in[14];
    float* outp = (float*)d_out;

    // workspace carve-up (~26 MB), 256B-aligned
    char* w = (char*)d_ws;
    size_t off = 0;
    auto alloc = [&](size_t bytes) { size_t r = off; off += (bytes + 255) & ~(size_t)255; return r; };
    int*   counts  = (int*)  (w + alloc((size_t)Nn * 4));
    int*   rowptr  = (int*)  (w + alloc((size_t)(Nn + 1) * 4));
    int*   cursor  = (int*)  (w + alloc((size_t)Nn * 4));
    int2*  me      = (int2*) (w + alloc((size_t)Ee * 8));
    float* st      = (float*)(w + alloc((size_t)Cc * 4));
    float* sw      = (float*)(w + alloc((size_t)Cc * 4));
    float* sb      = (float*)(w + alloc((size_t)Cc * 4));
    int*   so      = (int*)  (w + alloc((size_t)Cc * 4));
    int*   bsum    = (int*)  (w + alloc((size_t)SCAN_NB * 4));
    int*   boff    = (int*)  (w + alloc((size_t)SCAN_NB * 4));
    float* tabf    = (float*)(w + alloc((size_t)(Cc + 1) * 2 * Cc * 4));
    float* hpre    = (float*)(w + alloc((size_t)Nn * Cc * 4));
    (void)ws_size; (void)in_sizes; (void)n_in; (void)out_size;

    hipMemsetAsync(counts, 0, (size_t)Nn * 4, stream);
    prep_sort_kernel<<<1, 128, 0, stream>>>(Wl0, bl0, st, sw, sb, so);
    build_table_kernel<<<Cc + 1, 128, 0, stream>>>(sw, sb, so, Wl1, bl1, tabf);
    hist_kernel<<<(Ee + 255) / 256, 256, 0, stream>>>(ei, counts);
    scan_sum_kernel<<<SCAN_NB, SCAN_B, 0, stream>>>(counts, bsum);
    scan_bsum_kernel<<<1, 256, 0, stream>>>(bsum, boff, rowptr);
    scan_blocks_kernel<<<SCAN_NB, SCAN_B, 0, stream>>>(counts, boff, rowptr, cursor);
    fill_kernel<<<(Ee + 255) / 256, 256, 0, stream>>>(ei, eattr, st, cursor, me);

    const float4* tab = (const float4*)tabf;
    // conv 1: agg(x) -> hpre, mlp in-place on hpre
    aggregate_kernel<<<AGG_NB, 1024, 0, stream>>>(x, rowptr, me, tab, hpre);
    mlp2_kernel<<<(Nn + 63) / 64, 256, 0, stream>>>(hpre, W00, b00, W01, b01, hpre);
    // conv 2: agg(hpre) -> d_out, mlp in-place on d_out
    aggregate_kernel<<<AGG_NB, 1024, 0, stream>>>(hpre, rowptr, me, tab, outp);
    mlp2_kernel<<<(Nn + 63) / 64, 256, 0, stream>>>(outp, W10, b10, W11, b11, outp);
}

// Round 11
// 269.166 us; speedup vs baseline: 1.0849x; 1.0849x over previous
//
#include <hip/hip_runtime.h>
#include <hip/hip_fp16.h>
#include <math.h>

#define Nn 50000
#define Ee 800000
#define Cc 96

#define SCAN_B 256
#define SCAN_NB ((Nn + SCAN_B - 1) / SCAN_B)   // 196

typedef __attribute__((ext_vector_type(8))) __bf16 bf16x8;
typedef __attribute__((ext_vector_type(4))) float f32x4;

// split fp32 into hi/lo bf16 (truncation; lo captures next 8 mantissa bits)
__device__ inline void split_bf16(float v, unsigned short& hi, unsigned short& lo) {
    unsigned u = __float_as_uint(v);
    hi = (unsigned short)(u >> 16);
    float rem = v - __uint_as_float(((unsigned)hi) << 16);
    lo = (unsigned short)(__float_as_uint(rem) >> 16);
}

// ============ prep: sort linear0 hidden units by relu threshold ============
__global__ void prep_sort_kernel(const float* __restrict__ Wl0, const float* __restrict__ bl0,
                                 float* __restrict__ st, float* __restrict__ sw,
                                 float* __restrict__ sb, int* __restrict__ so) {
    __shared__ float t_s[Cc];
    int c = threadIdx.x;
    float w = 0.f, b = 0.f, t = 0.f;
    if (c < Cc) {
        w = Wl0[c]; b = bl0[c];
        t = (w != 0.0f) ? (-b / w) : INFINITY;
        t_s[c] = t;
    }
    __syncthreads();
    if (c < Cc) {
        int r = 0;
        for (int j = 0; j < Cc; ++j) {
            float tj = t_s[j];
            r += (tj < t || (tj == t && j < c)) ? 1 : 0;  // stable rank sort
        }
        st[r] = t; sw[r] = w; sb[r] = b; so[r] = c;
    }
}

// Table: tab[k][j] = float4{A[2j], B[2j], A[2j+1], B[2j+1]}, k = 0..96. 75 KB.
__global__ void build_table_kernel(const float* __restrict__ sw, const float* __restrict__ sb,
                                   const int* __restrict__ so, const float* __restrict__ Wl1,
                                   const float* __restrict__ bl1,
                                   float* __restrict__ tabf) {
    int k = blockIdx.x;          // 0..96
    int c2 = threadIdx.x;
    if (c2 >= Cc) return;
    float a = 0.f, bacc = bl1[c2];
    for (int i = 0; i < Cc; ++i) {
        float w = sw[i], b = sb[i];
        float wv = Wl1[so[i] * Cc + c2];
        bool act = (w > 0.f) ? (i < k) : ((w < 0.f) ? (i >= k) : (b > 0.f));
        if (act) { a = fmaf(w, wv, a); bacc = fmaf(b, wv, bacc); }
    }
    int base = k * (2 * Cc) + (c2 >> 1) * 4 + ((c2 & 1) << 1);
    tabf[base] = a;
    tabf[base + 1] = bacc;
}

// fp32 -> fp16 copy (vectorized float4 -> half4), for the gather path
__global__ __launch_bounds__(256) void cvt16_kernel(const float* __restrict__ in,
                                                    __half* __restrict__ out) {
    const int n4 = Nn * Cc / 4;   // 1.2M
    for (int i = blockIdx.x * blockDim.x + threadIdx.x; i < n4; i += gridDim.x * blockDim.x) {
        float4 v = ((const float4*)in)[i];
        __half2 h0 = __floats2half2_rn(v.x, v.y);
        __half2 h1 = __floats2half2_rn(v.z, v.w);
        ((__half2*)out)[2 * i] = h0;
        ((__half2*)out)[2 * i + 1] = h1;
    }
}

// ============ CSR build (by dst), reused for both convs ============
__global__ void hist_kernel(const int* __restrict__ ei, int* __restrict__ counts) {
    int e = blockIdx.x * blockDim.x + threadIdx.x;
    if (e >= Ee) return;
    int d = ei[Ee + e];
    if ((unsigned)d >= (unsigned)Nn) return;   // defensive: drop bad edges
    atomicAdd(&counts[d], 1);
}

__global__ __launch_bounds__(SCAN_B) void scan_sum_kernel(const int* __restrict__ counts,
                                                          int* __restrict__ bsum) {
    int i = blockIdx.x * SCAN_B + threadIdx.x;
    int v = (i < Nn) ? counts[i] : 0;
    for (int o = 32; o > 0; o >>= 1) v += __shfl_down(v, o, 64);
    __shared__ int ws[SCAN_B / 64];
    if ((threadIdx.x & 63) == 0) ws[threadIdx.x >> 6] = v;
    __syncthreads();
    if (threadIdx.x == 0) {
        int s = 0;
        for (int k = 0; k < SCAN_B / 64; ++k) s += ws[k];
        bsum[blockIdx.x] = s;
    }
}

__global__ __launch_bounds__(256) void scan_bsum_kernel(const int* __restrict__ bsum,
                                                        int* __restrict__ boff,
                                                        int* __restrict__ rowptr) {
    __shared__ int lds[256];
    int t = threadIdx.x;
    int v = (t < SCAN_NB) ? bsum[t] : 0;
    lds[t] = v;
    __syncthreads();
    for (int o = 1; o < 256; o <<= 1) {
        int u = (t >= o) ? lds[t - o] : 0;
        __syncthreads();
        lds[t] += u;
        __syncthreads();
    }
    if (t < SCAN_NB) boff[t] = lds[t] - v;
    if (t == 255) rowptr[Nn] = lds[255];
}

__global__ __launch_bounds__(SCAN_B) void scan_blocks_kernel(const int* __restrict__ counts,
                                                             const int* __restrict__ boff,
                                                             int* __restrict__ rowptr,
                                                             int* __restrict__ cursor) {
    __shared__ int lds[SCAN_B];
    int i = blockIdx.x * SCAN_B + threadIdx.x;
    int t = threadIdx.x;
    int v = (i < Nn) ? counts[i] : 0;
    lds[t] = v;
    __syncthreads();
    for (int o = 1; o < SCAN_B; o <<= 1) {
        int u = (t >= o) ? lds[t - o] : 0;
        __syncthreads();
        lds[t] += u;
        __syncthreads();
    }
    if (i < Nn) {
        int excl = lds[t] - v + boff[blockIdx.x];
        rowptr[i] = excl;
        cursor[i] = excl;
    }
}

// fill CSR: per edge store int2{ src | k<<20, bits(ea) }; k found once here.
__global__ void fill_kernel(const int* __restrict__ ei, const float* __restrict__ eattr,
                            const float* __restrict__ st, int* __restrict__ cursor,
                            int2* __restrict__ me) {
    __shared__ float ts[Cc];
    if (threadIdx.x < Cc) ts[threadIdx.x] = st[threadIdx.x];
    __syncthreads();
    int e = blockIdx.x * blockDim.x + threadIdx.x;
    if (e >= Ee) return;
    int s = ei[e];
    int d = ei[Ee + e];
    if ((unsigned)s >= (unsigned)Nn || (unsigned)d >= (unsigned)Nn) return;  // defensive
    float ea = eattr[e];
    int lo = 0, hi = Cc;          // k = count of thresholds < ea
    while (lo < hi) {
        int m = (lo + hi) >> 1;
        if (ts[m] < ea) lo = m + 1; else hi = m;
    }
    int pos = atomicAdd(&cursor[d], 1);
    if ((unsigned)pos >= (unsigned)Ee) return;  // defensive
    me[pos] = make_int2(s | (lo << 20), __float_as_int(ea));
}

// ============ aggregation: out[n] = feat[n] + sum_in relu(feat[src] + e) ============
// Persistent blocks, table in LDS; NEIGHBOR GATHER FROM FP16 COPY (halves the
// random-read traffic: 192 B/row vs 384 B). Self-term stays exact fp32.
// Lanes 0..47 own a channel PAIR: one half2 (4 B) per edge per lane.
#define AGG_NB 512
__global__ __launch_bounds__(1024) void aggregate_kernel(
        const float* __restrict__ feat, const __half* __restrict__ feat16,
        const int* __restrict__ rowptr, const int2* __restrict__ me,
        const float4* __restrict__ tab, float* __restrict__ out) {
    __shared__ float4 tl[(Cc + 1) * 48];   // 97*48*16 = 74496 B
    int tid = threadIdx.x;
    for (int i = tid; i < (Cc + 1) * 48; i += 1024) tl[i] = tab[i];
    __syncthreads();
    int wave = tid >> 6, lane = tid & 63;
    if (lane >= 48) return;               // no further syncs below
    int j = lane;                          // channel pair index, 0..47
    const float2* f2 = (const float2*)feat;
    const __half2* g2 = (const __half2*)feat16;
    for (int node = blockIdx.x * 16 + wave; node < Nn; node += AGG_NB * 16) {
        float2 acc = f2[(size_t)node * 48 + j];   // exact fp32 self-term
        int s = rowptr[node], e = rowptr[node + 1];
        int p = s;
        for (; p + 4 <= e; p += 4) {
            int2 m0 = me[p], m1 = me[p + 1], m2 = me[p + 2], m3 = me[p + 3];
            __half2 h0 = g2[(size_t)(m0.x & 0xFFFFF) * 48 + j];
            __half2 h1 = g2[(size_t)(m1.x & 0xFFFFF) * 48 + j];
            __half2 h2 = g2[(size_t)(m2.x & 0xFFFFF) * 48 + j];
            __half2 h3 = g2[(size_t)(m3.x & 0xFFFFF) * 48 + j];
            float4 t0 = tl[(m0.x >> 20) * 48 + j];
            float4 t1 = tl[(m1.x >> 20) * 48 + j];
            float4 t2 = tl[(m2.x >> 20) * 48 + j];
            float4 t3 = tl[(m3.x >> 20) * 48 + j];
            float2 f0 = __half22float2(h0), f1 = __half22float2(h1);
            float2 fb2 = __half22float2(h2), f3 = __half22float2(h3);
            float ea0 = __int_as_float(m0.y), ea1 = __int_as_float(m1.y);
            float ea2 = __int_as_float(m2.y), ea3 = __int_as_float(m3.y);
            acc.x += fmaxf(f0.x + fmaf(ea0, t0.x, t0.y), 0.f);
            acc.y += fmaxf(f0.y + fmaf(ea0, t0.z, t0.w), 0.f);
            acc.x += fmaxf(f1.x + fmaf(ea1, t1.x, t1.y), 0.f);
            acc.y += fmaxf(f1.y + fmaf(ea1, t1.z, t1.w), 0.f);
            acc.x += fmaxf(fb2.x + fmaf(ea2, t2.x, t2.y), 0.f);
            acc.y += fmaxf(fb2.y + fmaf(ea2, t2.z, t2.w), 0.f);
            acc.x += fmaxf(f3.x + fmaf(ea3, t3.x, t3.y), 0.f);
            acc.y += fmaxf(f3.y + fmaf(ea3, t3.z, t3.w), 0.f);
        }
        for (; p < e; ++p) {
            int2 m0 = me[p];
            float2 f0 = __half22float2(g2[(size_t)(m0.x & 0xFFFFF) * 48 + j]);
            float4 t0 = tl[(m0.x >> 20) * 48 + j];
            float ea0 = __int_as_float(m0.y);
            acc.x += fmaxf(f0.x + fmaf(ea0, t0.x, t0.y), 0.f);
            acc.y += fmaxf(f0.y + fmaf(ea0, t0.z, t0.w), 0.f);
        }
        ((float2*)out)[(size_t)node * 48 + j] = acc;
    }
}

// ============ fused 2-layer node MLP via bf16x3 MFMA ============
// out = relu(relu(in@W1+b1)@W2+b2). Optionally also emits fp16 copy of the
// output (out16) for the next conv's gather path. IN-PLACE SAFE.
#define MLP_PAD 104
__global__ __launch_bounds__(256) void mlp2_kernel(
        const float* __restrict__ in, const float* __restrict__ W1g, const float* __restrict__ b1g,
        const float* __restrict__ W2g, const float* __restrict__ b2g, float* __restrict__ out,
        __half* __restrict__ out16) {
    __shared__ unsigned short xh[64 * MLP_PAD], xl[64 * MLP_PAD];
    __shared__ unsigned short wth[96 * MLP_PAD], wtl[96 * MLP_PAD];
    __shared__ float bb1[Cc], bb2[Cc];
    int tid = threadIdx.x;
    int row0 = blockIdx.x * 64;

    for (int t = 0; t < 24; ++t) {
        int idx = tid + t * 256;                 // 0..6143
        int r = idx / Cc, c = idx - r * Cc;
        int gr = row0 + r;
        float v = (gr < Nn) ? in[(size_t)gr * Cc + c] : 0.f;
        unsigned short hi, lo;
        split_bf16(v, hi, lo);
        xh[r * MLP_PAD + c] = hi; xl[r * MLP_PAD + c] = lo;
    }
    for (int t = 0; t < 36; ++t) {
        int idx = tid + t * 256;                 // 0..9215
        int k = idx / Cc, n = idx - k * Cc;
        unsigned short hi, lo;
        split_bf16(W1g[idx], hi, lo);
        wth[n * MLP_PAD + k] = hi; wtl[n * MLP_PAD + k] = lo;
    }
    if (tid < Cc) { bb1[tid] = b1g[tid]; bb2[tid] = b2g[tid]; }
    __syncthreads();

    int lane = tid & 63, w = tid >> 6;
    int li = lane & 15, lg = lane >> 4;          // li: m/n idx; lg: k-group
    int arow = w * 16 + li;                      // A row (A: row=lane&15, k=8*lg+e)

    f32x4 acc[6];
    // ---- layer 1 ----
    for (int nt = 0; nt < 6; ++nt) {
        float bv = bb1[nt * 16 + li];
        acc[nt] = (f32x4){bv, bv, bv, bv};
    }
    for (int k0 = 0; k0 < Cc; k0 += 32) {
        int ko = k0 + lg * 8;
        bf16x8 ah = *(const bf16x8*)&xh[arow * MLP_PAD + ko];
        bf16x8 al = *(const bf16x8*)&xl[arow * MLP_PAD + ko];
        for (int nt = 0; nt < 6; ++nt) {
            bf16x8 bh = *(const bf16x8*)&wth[(nt * 16 + li) * MLP_PAD + ko];
            bf16x8 bl = *(const bf16x8*)&wtl[(nt * 16 + li) * MLP_PAD + ko];
            acc[nt] = __builtin_amdgcn_mfma_f32_16x16x32_bf16(ah, bh, acc[nt], 0, 0, 0);
            acc[nt] = __builtin_amdgcn_mfma_f32_16x16x32_bf16(ah, bl, acc[nt], 0, 0, 0);
            acc[nt] = __builtin_amdgcn_mfma_f32_16x16x32_bf16(al, bh, acc[nt], 0, 0, 0);
        }
    }
    __syncthreads();   // all waves done reading wt & x
    for (int nt = 0; nt < 6; ++nt) {
        for (int r = 0; r < 4; ++r) {
            float v = fmaxf(acc[nt][r], 0.f);
            int row = w * 16 + lg * 4 + r;
            int col = nt * 16 + li;
            unsigned short hi, lo;
            split_bf16(v, hi, lo);
            xh[row * MLP_PAD + col] = hi; xl[row * MLP_PAD + col] = lo;
        }
    }
    for (int t = 0; t < 36; ++t) {
        int idx = tid + t * 256;
        int k = idx / Cc, n = idx - k * Cc;
        unsigned short hi, lo;
        split_bf16(W2g[idx], hi, lo);
        wth[n * MLP_PAD + k] = hi; wtl[n * MLP_PAD + k] = lo;
    }
    __syncthreads();

    // ---- layer 2 ----
    for (int nt = 0; nt < 6; ++nt) {
        float bv = bb2[nt * 16 + li];
        acc[nt] = (f32x4){bv, bv, bv, bv};
    }
    for (int k0 = 0; k0 < Cc; k0 += 32) {
        int ko = k0 + lg * 8;
        bf16x8 ah = *(const bf16x8*)&xh[arow * MLP_PAD + ko];
        bf16x8 al = *(const bf16x8*)&xl[arow * MLP_PAD + ko];
        for (int nt = 0; nt < 6; ++nt) {
            bf16x8 bh = *(const bf16x8*)&wth[(nt * 16 + li) * MLP_PAD + ko];
            bf16x8 bl = *(const bf16x8*)&wtl[(nt * 16 + li) * MLP_PAD + ko];
            acc[nt] = __builtin_amdgcn_mfma_f32_16x16x32_bf16(ah, bh, acc[nt], 0, 0, 0);
            acc[nt] = __builtin_amdgcn_mfma_f32_16x16x32_bf16(ah, bl, acc[nt], 0, 0, 0);
            acc[nt] = __builtin_amdgcn_mfma_f32_16x16x32_bf16(al, bh, acc[nt], 0, 0, 0);
        }
    }
    for (int nt = 0; nt < 6; ++nt) {
        for (int r = 0; r < 4; ++r) {
            int grow = row0 + w * 16 + lg * 4 + r;
            if (grow < Nn) {
                float v = fmaxf(acc[nt][r], 0.f);
                out[(size_t)grow * Cc + nt * 16 + li] = v;
                if (out16) out16[(size_t)grow * Cc + nt * 16 + li] = __float2half_rn(v);
            }
        }
    }
}

extern "C" void kernel_launch(void* const* d_in, const int* in_sizes, int n_in,
                              void* d_out, int out_size, void* d_ws, size_t ws_size,
                              hipStream_t stream) {
    const float* x     = (const float*)d_in[0];
    const int*   ei    = (const int*)d_in[1];     // int64 in ref -> int32 from harness
    const float* eattr = (const float*)d_in[2];
    const float* Wl0   = (const float*)d_in[3];
    const float* bl0   = (const float*)d_in[4];
    const float* Wl1   = (const float*)d_in[5];
    const float* bl1   = (const float*)d_in[6];
    const float* W00   = (const float*)d_in[7];
    const float* b00   = (const float*)d_in[8];
    const float* W01   = (const float*)d_in[9];
    const float* b01   = (const float*)d_in[10];
    const float* W10   = (const float*)d_in[11];
    const float* b10   = (const float*)d_in[12];
    const float* W11   = (const float*)d_in[13];
    const float* b11   = (const float*)d_in[14];
    float* outp = (float*)d_out;

    // workspace carve-up (~45 MB), 256B-aligned
    char* w = (char*)d_ws;
    size_t off = 0;
    auto alloc = [&](size_t bytes) { size_t r = off; off += (bytes + 255) & ~(size_t)255; return r; };
    int*   counts  = (int*)  (w + alloc((size_t)Nn * 4));
    int*   rowptr  = (int*)  (w + alloc((size_t)(Nn + 1) * 4));
    int*   cursor  = (int*)  (w + alloc((size_t)Nn * 4));
    int2*  me      = (int2*) (w + alloc((size_t)Ee * 8));
    float* st      = (float*)(w + alloc((size_t)Cc * 4));
    float* sw      = (float*)(w + alloc((size_t)Cc * 4));
    float* sb      = (float*)(w + alloc((size_t)Cc * 4));
    int*   so      = (int*)  (w + alloc((size_t)Cc * 4));
    int*   bsum    = (int*)  (w + alloc((size_t)SCAN_NB * 4));
    int*   boff    = (int*)  (w + alloc((size_t)SCAN_NB * 4));
    float* tabf    = (float*)(w + alloc((size_t)(Cc + 1) * 2 * Cc * 4));
    float* hpre    = (float*)(w + alloc((size_t)Nn * Cc * 4));
    __half* g16    = (__half*)(w + alloc((size_t)Nn * Cc * 2));  // fp16 gather copy
    (void)ws_size; (void)in_sizes; (void)n_in; (void)out_size;

    hipMemsetAsync(counts, 0, (size_t)Nn * 4, stream);
    prep_sort_kernel<<<1, 128, 0, stream>>>(Wl0, bl0, st, sw, sb, so);
    build_table_kernel<<<Cc + 1, 128, 0, stream>>>(sw, sb, so, Wl1, bl1, tabf);
    hist_kernel<<<(Ee + 255) / 256, 256, 0, stream>>>(ei, counts);
    scan_sum_kernel<<<SCAN_NB, SCAN_B, 0, stream>>>(counts, bsum);
    scan_bsum_kernel<<<1, 256, 0, stream>>>(bsum, boff, rowptr);
    scan_blocks_kernel<<<SCAN_NB, SCAN_B, 0, stream>>>(counts, boff, rowptr, cursor);
    fill_kernel<<<(Ee + 255) / 256, 256, 0, stream>>>(ei, eattr, st, cursor, me);
    cvt16_kernel<<<1024, 256, 0, stream>>>(x, g16);   // x -> fp16 gather copy

    const float4* tab = (const float4*)tabf;
    // conv 1: agg(x, x16) -> hpre; mlp in-place on hpre, also emits h16 into g16
    aggregate_kernel<<<AGG_NB, 1024, 0, stream>>>(x, g16, rowptr, me, tab, hpre);
    mlp2_kernel<<<(Nn + 63) / 64, 256, 0, stream>>>(hpre, W00, b00, W01, b01, hpre, g16);
    // conv 2: agg(h, h16) -> d_out; final mlp in-place on d_out (no fp16 emit)
    aggregate_kernel<<<AGG_NB, 1024, 0, stream>>>(hpre, g16, rowptr, me, tab, outp);
    mlp2_kernel<<<(Nn + 63) / 64, 256, 0, stream>>>(outp, W10, b10, W11, b11, outp, (__half*)nullptr);
}

// Round 12
// 248.054 us; speedup vs baseline: 1.1772x; 1.0851x over previous
//
#include <hip/hip_runtime.h>
#include <hip/hip_fp16.h>
#include <math.h>

#define Nn 50000
#define Ee 800000
#define Cc 96

#define SCAN_B 256
#define SCAN_NB ((Nn + SCAN_B - 1) / SCAN_B)   // 196

// bucketed CSR-fill geometry
#define NPB 196                                 // nodes per bucket
#define NBK 256                                 // buckets (256*196 >= 50000)
#define P2_T 512
#define P2_E 4
#define P2_BLK (P2_T * P2_E)                    // 2048 edges/block
#define NB2 ((Ee + P2_BLK - 1) / P2_BLK)        // 391 blocks

typedef __attribute__((ext_vector_type(8))) __bf16 bf16x8;
typedef __attribute__((ext_vector_type(4))) float f32x4;

// split fp32 into hi/lo bf16 (truncation; lo captures next 8 mantissa bits)
__device__ inline void split_bf16(float v, unsigned short& hi, unsigned short& lo) {
    unsigned u = __float_as_uint(v);
    hi = (unsigned short)(u >> 16);
    float rem = v - __uint_as_float(((unsigned)hi) << 16);
    lo = (unsigned short)(__float_as_uint(rem) >> 16);
}

// ============ prep: sort linear0 hidden units by relu threshold ============
__global__ void prep_sort_kernel(const float* __restrict__ Wl0, const float* __restrict__ bl0,
                                 float* __restrict__ st, float* __restrict__ sw,
                                 float* __restrict__ sb, int* __restrict__ so) {
    __shared__ float t_s[Cc];
    int c = threadIdx.x;
    float w = 0.f, b = 0.f, t = 0.f;
    if (c < Cc) {
        w = Wl0[c]; b = bl0[c];
        t = (w != 0.0f) ? (-b / w) : INFINITY;
        t_s[c] = t;
    }
    __syncthreads();
    if (c < Cc) {
        int r = 0;
        for (int j = 0; j < Cc; ++j) {
            float tj = t_s[j];
            r += (tj < t || (tj == t && j < c)) ? 1 : 0;  // stable rank sort
        }
        st[r] = t; sw[r] = w; sb[r] = b; so[r] = c;
    }
}

// Table: tab[k][j] = float4{A[2j], B[2j], A[2j+1], B[2j+1]}, k = 0..96. 75 KB.
__global__ void build_table_kernel(const float* __restrict__ sw, const float* __restrict__ sb,
                                   const int* __restrict__ so, const float* __restrict__ Wl1,
                                   const float* __restrict__ bl1,
                                   float* __restrict__ tabf) {
    int k = blockIdx.x;          // 0..96
    int c2 = threadIdx.x;
    if (c2 >= Cc) return;
    float a = 0.f, bacc = bl1[c2];
    for (int i = 0; i < Cc; ++i) {
        float w = sw[i], b = sb[i];
        float wv = Wl1[so[i] * Cc + c2];
        bool act = (w > 0.f) ? (i < k) : ((w < 0.f) ? (i >= k) : (b > 0.f));
        if (act) { a = fmaf(w, wv, a); bacc = fmaf(b, wv, bacc); }
    }
    int base = k * (2 * Cc) + (c2 >> 1) * 4 + ((c2 & 1) << 1);
    tabf[base] = a;
    tabf[base + 1] = bacc;
}

// fp32 -> fp16 copy (vectorized float4 -> half4), for the gather path
__global__ __launch_bounds__(256) void cvt16_kernel(const float* __restrict__ in,
                                                    __half* __restrict__ out) {
    const int n4 = Nn * Cc / 4;   // 1.2M
    for (int i = blockIdx.x * blockDim.x + threadIdx.x; i < n4; i += gridDim.x * blockDim.x) {
        float4 v = ((const float4*)in)[i];
        __half2 h0 = __floats2half2_rn(v.x, v.y);
        __half2 h1 = __floats2half2_rn(v.z, v.w);
        ((__half2*)out)[2 * i] = h0;
        ((__half2*)out)[2 * i + 1] = h1;
    }
}

// ============ CSR rowptr (per-node counts + scans) ============
// valid() must be IDENTICAL in hist / bucket_hist / pass2 to keep counts consistent.
__device__ inline bool edge_valid(int s, int d) {
    return (unsigned)s < (unsigned)Nn && (unsigned)d < (unsigned)Nn;
}

__global__ void hist_kernel(const int* __restrict__ ei, int* __restrict__ counts) {
    int e = blockIdx.x * blockDim.x + threadIdx.x;
    if (e >= Ee) return;
    int s = ei[e], d = ei[Ee + e];
    if (!edge_valid(s, d)) return;
    atomicAdd(&counts[d], 1);
}

__global__ __launch_bounds__(SCAN_B) void scan_sum_kernel(const int* __restrict__ counts,
                                                          int* __restrict__ bsum) {
    int i = blockIdx.x * SCAN_B + threadIdx.x;
    int v = (i < Nn) ? counts[i] : 0;
    for (int o = 32; o > 0; o >>= 1) v += __shfl_down(v, o, 64);
    __shared__ int ws[SCAN_B / 64];
    if ((threadIdx.x & 63) == 0) ws[threadIdx.x >> 6] = v;
    __syncthreads();
    if (threadIdx.x == 0) {
        int s = 0;
        for (int k = 0; k < SCAN_B / 64; ++k) s += ws[k];
        bsum[blockIdx.x] = s;
    }
}

__global__ __launch_bounds__(256) void scan_bsum_kernel(const int* __restrict__ bsum,
                                                        int* __restrict__ boff,
                                                        int* __restrict__ rowptr) {
    __shared__ int lds[256];
    int t = threadIdx.x;
    int v = (t < SCAN_NB) ? bsum[t] : 0;
    lds[t] = v;
    __syncthreads();
    for (int o = 1; o < 256; o <<= 1) {
        int u = (t >= o) ? lds[t - o] : 0;
        __syncthreads();
        lds[t] += u;
        __syncthreads();
    }
    if (t < SCAN_NB) boff[t] = lds[t] - v;
    if (t == 255) rowptr[Nn] = lds[255];
}

__global__ __launch_bounds__(SCAN_B) void scan_blocks_kernel(const int* __restrict__ counts,
                                                             const int* __restrict__ boff,
                                                             int* __restrict__ rowptr) {
    __shared__ int lds[SCAN_B];
    int i = blockIdx.x * SCAN_B + threadIdx.x;
    int t = threadIdx.x;
    int v = (i < Nn) ? counts[i] : 0;
    lds[t] = v;
    __syncthreads();
    for (int o = 1; o < SCAN_B; o <<= 1) {
        int u = (t >= o) ? lds[t - o] : 0;
        __syncthreads();
        lds[t] += u;
        __syncthreads();
    }
    if (i < Nn) rowptr[i] = lds[t] - v + boff[blockIdx.x];
}

// ============ bucketed CSR fill (kills scattered-write amplification) ============
// phase 1: per-(block,bucket) histogram -> bmat[NB2][NBK]
__global__ __launch_bounds__(P2_T) void bucket_hist_kernel(const int* __restrict__ ei,
                                                           int* __restrict__ bmat) {
    __shared__ int cnt[NBK];
    int tid = threadIdx.x;
    for (int i = tid; i < NBK; i += P2_T) cnt[i] = 0;
    __syncthreads();
    int base = blockIdx.x * P2_BLK;
    for (int t = 0; t < P2_E; ++t) {
        int e = base + tid + t * P2_T;
        if (e < Ee) {
            int s = ei[e], d = ei[Ee + e];
            if (edge_valid(s, d)) atomicAdd(&cnt[d / NPB], 1);
        }
    }
    __syncthreads();
    for (int i = tid; i < NBK; i += P2_T) bmat[blockIdx.x * NBK + i] = cnt[i];
}

// phase 2: per-bucket exclusive scan over blocks -> boffmat[NB2][NBK] (global positions)
__global__ __launch_bounds__(512) void bmat_scan_kernel(const int* __restrict__ bmat,
                                                        const int* __restrict__ rowptr,
                                                        int* __restrict__ boffmat) {
    __shared__ int lds[512];
    int bk = blockIdx.x, t = threadIdx.x;
    int v = (t < NB2) ? bmat[t * NBK + bk] : 0;
    lds[t] = v;
    __syncthreads();
    for (int o = 1; o < 512; o <<= 1) {
        int u = (t >= o) ? lds[t - o] : 0;
        __syncthreads();
        lds[t] += u;
        __syncthreads();
    }
    if (t < NB2) boffmat[t * NBK + bk] = rowptr[bk * NPB] + lds[t] - v;
}

// phase 3: scatter edges into bucket-segmented stage[] with block-contiguous runs.
// stage entry: { src | dlocal<<16 , bits(ea) }  (src<2^16, dlocal<196<2^8)
__global__ __launch_bounds__(P2_T) void pass2_kernel(const int* __restrict__ ei,
                                                     const float* __restrict__ eattr,
                                                     const int* __restrict__ boffmat,
                                                     int2* __restrict__ stage) {
    __shared__ int curs[NBK];
    int tid = threadIdx.x;
    for (int i = tid; i < NBK; i += P2_T) curs[i] = boffmat[blockIdx.x * NBK + i];
    __syncthreads();
    int base = blockIdx.x * P2_BLK;
    for (int t = 0; t < P2_E; ++t) {
        int e = base + tid + t * P2_T;
        if (e >= Ee) continue;
        int s = ei[e], d = ei[Ee + e];
        if (!edge_valid(s, d)) continue;
        int bk = d / NPB, dl = d - bk * NPB;
        int pos = atomicAdd(&curs[bk], 1);
        stage[pos] = make_int2(s | (dl << 16), __float_as_int(eattr[e]));
    }
}

// phase 4: per-bucket fine placement. One block owns one bucket's me-region, so
// all scattered me writes for a region come from ONE CU -> lines fully dirtied
// in one L2 -> writeback ~= logical bytes (6.4 MB total, was 52 MB).
__global__ __launch_bounds__(512) void pass3_kernel(const int2* __restrict__ stage,
                                                    const int* __restrict__ rowptr,
                                                    const float* __restrict__ st,
                                                    int2* __restrict__ me) {
    __shared__ int curs[NPB];
    __shared__ float ts[Cc];
    int bk = blockIdx.x, tid = threadIdx.x;
    int nstart = bk * NPB;
    int nend = min(nstart + NPB, Nn);
    if (tid < Cc) ts[tid] = st[tid];
    for (int i = tid; i < nend - nstart; i += 512) curs[i] = rowptr[nstart + i];
    __syncthreads();
    int sstart = rowptr[nstart], send = rowptr[nend];
    for (int p = sstart + tid; p < send; p += 512) {
        int2 sv = stage[p];
        int s = sv.x & 0xFFFF;
        int dl = (sv.x >> 16) & 0xFF;
        float ea = __int_as_float(sv.y);
        int lo = 0, hi = Cc;
        while (lo < hi) { int m = (lo + hi) >> 1; if (ts[m] < ea) lo = m + 1; else hi = m; }
        int pos = atomicAdd(&curs[dl], 1);
        me[pos] = make_int2(s | (lo << 20), sv.y);
    }
}

// ============ aggregation: out[n] = feat[n] + sum_in relu(feat[src] + e) ============
// Persistent blocks, table in LDS; neighbor gather from fp16 copy (192 B/row).
#define AGG_NB 512
__global__ __launch_bounds__(1024) void aggregate_kernel(
        const float* __restrict__ feat, const __half* __restrict__ feat16,
        const int* __restrict__ rowptr, const int2* __restrict__ me,
        const float4* __restrict__ tab, float* __restrict__ out) {
    __shared__ float4 tl[(Cc + 1) * 48];   // 97*48*16 = 74496 B
    int tid = threadIdx.x;
    for (int i = tid; i < (Cc + 1) * 48; i += 1024) tl[i] = tab[i];
    __syncthreads();
    int wave = tid >> 6, lane = tid & 63;
    if (lane >= 48) return;               // no further syncs below
    int j = lane;                          // channel pair index, 0..47
    const float2* f2 = (const float2*)feat;
    const __half2* g2 = (const __half2*)feat16;
    for (int node = blockIdx.x * 16 + wave; node < Nn; node += AGG_NB * 16) {
        float2 acc = f2[(size_t)node * 48 + j];   // exact fp32 self-term
        int s = rowptr[node], e = rowptr[node + 1];
        int p = s;
        for (; p + 4 <= e; p += 4) {
            int2 m0 = me[p], m1 = me[p + 1], m2 = me[p + 2], m3 = me[p + 3];
            __half2 h0 = g2[(size_t)(m0.x & 0xFFFFF) * 48 + j];
            __half2 h1 = g2[(size_t)(m1.x & 0xFFFFF) * 48 + j];
            __half2 h2 = g2[(size_t)(m2.x & 0xFFFFF) * 48 + j];
            __half2 h3 = g2[(size_t)(m3.x & 0xFFFFF) * 48 + j];
            float4 t0 = tl[(m0.x >> 20) * 48 + j];
            float4 t1 = tl[(m1.x >> 20) * 48 + j];
            float4 t2 = tl[(m2.x >> 20) * 48 + j];
            float4 t3 = tl[(m3.x >> 20) * 48 + j];
            float2 f0 = __half22float2(h0), f1 = __half22float2(h1);
            float2 fb2 = __half22float2(h2), f3 = __half22float2(h3);
            float ea0 = __int_as_float(m0.y), ea1 = __int_as_float(m1.y);
            float ea2 = __int_as_float(m2.y), ea3 = __int_as_float(m3.y);
            acc.x += fmaxf(f0.x + fmaf(ea0, t0.x, t0.y), 0.f);
            acc.y += fmaxf(f0.y + fmaf(ea0, t0.z, t0.w), 0.f);
            acc.x += fmaxf(f1.x + fmaf(ea1, t1.x, t1.y), 0.f);
            acc.y += fmaxf(f1.y + fmaf(ea1, t1.z, t1.w), 0.f);
            acc.x += fmaxf(fb2.x + fmaf(ea2, t2.x, t2.y), 0.f);
            acc.y += fmaxf(fb2.y + fmaf(ea2, t2.z, t2.w), 0.f);
            acc.x += fmaxf(f3.x + fmaf(ea3, t3.x, t3.y), 0.f);
            acc.y += fmaxf(f3.y + fmaf(ea3, t3.z, t3.w), 0.f);
        }
        for (; p < e; ++p) {
            int2 m0 = me[p];
            float2 f0 = __half22float2(g2[(size_t)(m0.x & 0xFFFFF) * 48 + j]);
            float4 t0 = tl[(m0.x >> 20) * 48 + j];
            float ea0 = __int_as_float(m0.y);
            acc.x += fmaxf(f0.x + fmaf(ea0, t0.x, t0.y), 0.f);
            acc.y += fmaxf(f0.y + fmaf(ea0, t0.z, t0.w), 0.f);
        }
        ((float2*)out)[(size_t)node * 48 + j] = acc;
    }
}

// ============ fused 2-layer node MLP via bf16x3 MFMA ============
#define MLP_PAD 104
__global__ __launch_bounds__(256) void mlp2_kernel(
        const float* __restrict__ in, const float* __restrict__ W1g, const float* __restrict__ b1g,
        const float* __restrict__ W2g, const float* __restrict__ b2g, float* __restrict__ out,
        __half* __restrict__ out16) {
    __shared__ unsigned short xh[64 * MLP_PAD], xl[64 * MLP_PAD];
    __shared__ unsigned short wth[96 * MLP_PAD], wtl[96 * MLP_PAD];
    __shared__ float bb1[Cc], bb2[Cc];
    int tid = threadIdx.x;
    int row0 = blockIdx.x * 64;

    for (int t = 0; t < 24; ++t) {
        int idx = tid + t * 256;                 // 0..6143
        int r = idx / Cc, c = idx - r * Cc;
        int gr = row0 + r;
        float v = (gr < Nn) ? in[(size_t)gr * Cc + c] : 0.f;
        unsigned short hi, lo;
        split_bf16(v, hi, lo);
        xh[r * MLP_PAD + c] = hi; xl[r * MLP_PAD + c] = lo;
    }
    for (int t = 0; t < 36; ++t) {
        int idx = tid + t * 256;                 // 0..9215
        int k = idx / Cc, n = idx - k * Cc;
        unsigned short hi, lo;
        split_bf16(W1g[idx], hi, lo);
        wth[n * MLP_PAD + k] = hi; wtl[n * MLP_PAD + k] = lo;
    }
    if (tid < Cc) { bb1[tid] = b1g[tid]; bb2[tid] = b2g[tid]; }
    __syncthreads();

    int lane = tid & 63, w = tid >> 6;
    int li = lane & 15, lg = lane >> 4;          // li: m/n idx; lg: k-group
    int arow = w * 16 + li;                      // A row (A: row=lane&15, k=8*lg+e)

    f32x4 acc[6];
    // ---- layer 1 ----
    for (int nt = 0; nt < 6; ++nt) {
        float bv = bb1[nt * 16 + li];
        acc[nt] = (f32x4){bv, bv, bv, bv};
    }
    for (int k0 = 0; k0 < Cc; k0 += 32) {
        int ko = k0 + lg * 8;
        bf16x8 ah = *(const bf16x8*)&xh[arow * MLP_PAD + ko];
        bf16x8 al = *(const bf16x8*)&xl[arow * MLP_PAD + ko];
        for (int nt = 0; nt < 6; ++nt) {
            bf16x8 bh = *(const bf16x8*)&wth[(nt * 16 + li) * MLP_PAD + ko];
            bf16x8 bl = *(const bf16x8*)&wtl[(nt * 16 + li) * MLP_PAD + ko];
            acc[nt] = __builtin_amdgcn_mfma_f32_16x16x32_bf16(ah, bh, acc[nt], 0, 0, 0);
            acc[nt] = __builtin_amdgcn_mfma_f32_16x16x32_bf16(ah, bl, acc[nt], 0, 0, 0);
            acc[nt] = __builtin_amdgcn_mfma_f32_16x16x32_bf16(al, bh, acc[nt], 0, 0, 0);
        }
    }
    __syncthreads();   // all waves done reading wt & x
    for (int nt = 0; nt < 6; ++nt) {
        for (int r = 0; r < 4; ++r) {
            float v = fmaxf(acc[nt][r], 0.f);
            int row = w * 16 + lg * 4 + r;
            int col = nt * 16 + li;
            unsigned short hi, lo;
            split_bf16(v, hi, lo);
            xh[row * MLP_PAD + col] = hi; xl[row * MLP_PAD + col] = lo;
        }
    }
    for (int t = 0; t < 36; ++t) {
        int idx = tid + t * 256;
        int k = idx / Cc, n = idx - k * Cc;
        unsigned short hi, lo;
        split_bf16(W2g[idx], hi, lo);
        wth[n * MLP_PAD + k] = hi; wtl[n * MLP_PAD + k] = lo;
    }
    __syncthreads();

    // ---- layer 2 ----
    for (int nt = 0; nt < 6; ++nt) {
        float bv = bb2[nt * 16 + li];
        acc[nt] = (f32x4){bv, bv, bv, bv};
    }
    for (int k0 = 0; k0 < Cc; k0 += 32) {
        int ko = k0 + lg * 8;
        bf16x8 ah = *(const bf16x8*)&xh[arow * MLP_PAD + ko];
        bf16x8 al = *(const bf16x8*)&xl[arow * MLP_PAD + ko];
        for (int nt = 0; nt < 6; ++nt) {
            bf16x8 bh = *(const bf16x8*)&wth[(nt * 16 + li) * MLP_PAD + ko];
            bf16x8 bl = *(const bf16x8*)&wtl[(nt * 16 + li) * MLP_PAD + ko];
            acc[nt] = __builtin_amdgcn_mfma_f32_16x16x32_bf16(ah, bh, acc[nt], 0, 0, 0);
            acc[nt] = __builtin_amdgcn_mfma_f32_16x16x32_bf16(ah, bl, acc[nt], 0, 0, 0);
            acc[nt] = __builtin_amdgcn_mfma_f32_16x16x32_bf16(al, bh, acc[nt], 0, 0, 0);
        }
    }
    for (int nt = 0; nt < 6; ++nt) {
        for (int r = 0; r < 4; ++r) {
            int grow = row0 + w * 16 + lg * 4 + r;
            if (grow < Nn) {
                float v = fmaxf(acc[nt][r], 0.f);
                out[(size_t)grow * Cc + nt * 16 + li] = v;
                if (out16) out16[(size_t)grow * Cc + nt * 16 + li] = __float2half_rn(v);
            }
        }
    }
}

extern "C" void kernel_launch(void* const* d_in, const int* in_sizes, int n_in,
                              void* d_out, int out_size, void* d_ws, size_t ws_size,
                              hipStream_t stream) {
    const float* x     = (const float*)d_in[0];
    const int*   ei    = (const int*)d_in[1];     // int64 in ref -> int32 from harness
    const float* eattr = (const float*)d_in[2];
    const float* Wl0   = (const float*)d_in[3];
    const float* bl0   = (const float*)d_in[4];
    const float* Wl1   = (const float*)d_in[5];
    const float* bl1   = (const float*)d_in[6];
    const float* W00   = (const float*)d_in[7];
    const float* b00   = (const float*)d_in[8];
    const float* W01   = (const float*)d_in[9];
    const float* b01   = (const float*)d_in[10];
    const float* W10   = (const float*)d_in[11];
    const float* b10   = (const float*)d_in[12];
    const float* W11   = (const float*)d_in[13];
    const float* b11   = (const float*)d_in[14];
    float* outp = (float*)d_out;

    // workspace carve-up (~37 MB), 256B-aligned
    char* w = (char*)d_ws;
    size_t off = 0;
    auto alloc = [&](size_t bytes) { size_t r = off; off += (bytes + 255) & ~(size_t)255; return r; };
    int*   counts  = (int*)  (w + alloc((size_t)Nn * 4));
    int*   rowptr  = (int*)  (w + alloc((size_t)(Nn + 1) * 4));
    int2*  me      = (int2*) (w + alloc((size_t)Ee * 8));
    float* st      = (float*)(w + alloc((size_t)Cc * 4));
    float* sw      = (float*)(w + alloc((size_t)Cc * 4));
    float* sb      = (float*)(w + alloc((size_t)Cc * 4));
    int*   so      = (int*)  (w + alloc((size_t)Cc * 4));
    int*   bsum    = (int*)  (w + alloc((size_t)SCAN_NB * 4));
    int*   boff    = (int*)  (w + alloc((size_t)SCAN_NB * 4));
    int*   bmat    = (int*)  (w + alloc((size_t)NB2 * NBK * 4));
    int*   boffmat = (int*)  (w + alloc((size_t)NB2 * NBK * 4));
    float* tabf    = (float*)(w + alloc((size_t)(Cc + 1) * 2 * Cc * 4));
    float* hpre    = (float*)(w + alloc((size_t)Nn * Cc * 4));
    __half* g16    = (__half*)(w + alloc((size_t)Nn * Cc * 2));  // fp16 gather copy
    int2*  stage   = (int2*)hpre;   // 6.4 MB staging aliases hpre (dead until aggregate)
    (void)ws_size; (void)in_sizes; (void)n_in; (void)out_size;

    hipMemsetAsync(counts, 0, (size_t)Nn * 4, stream);
    prep_sort_kernel<<<1, 128, 0, stream>>>(Wl0, bl0, st, sw, sb, so);
    build_table_kernel<<<Cc + 1, 128, 0, stream>>>(sw, sb, so, Wl1, bl1, tabf);
    hist_kernel<<<(Ee + 255) / 256, 256, 0, stream>>>(ei, counts);
    scan_sum_kernel<<<SCAN_NB, SCAN_B, 0, stream>>>(counts, bsum);
    scan_bsum_kernel<<<1, 256, 0, stream>>>(bsum, boff, rowptr);
    scan_blocks_kernel<<<SCAN_NB, SCAN_B, 0, stream>>>(counts, boff, rowptr);
    // bucketed fill
    bucket_hist_kernel<<<NB2, P2_T, 0, stream>>>(ei, bmat);
    bmat_scan_kernel<<<NBK, 512, 0, stream>>>(bmat, rowptr, boffmat);
    pass2_kernel<<<NB2, P2_T, 0, stream>>>(ei, eattr, boffmat, stage);
    pass3_kernel<<<NBK, 512, 0, stream>>>(stage, rowptr, st, me);
    cvt16_kernel<<<1024, 256, 0, stream>>>(x, g16);   // x -> fp16 gather copy

    const float4* tab = (const float4*)tabf;
    // conv 1: agg(x, x16) -> hpre; mlp in-place on hpre, also emits h16 into g16
    aggregate_kernel<<<AGG_NB, 1024, 0, stream>>>(x, g16, rowptr, me, tab, hpre);
    mlp2_kernel<<<(Nn + 63) / 64, 256, 0, stream>>>(hpre, W00, b00, W01, b01, hpre, g16);
    // conv 2: agg(h, h16) -> d_out; final mlp in-place on d_out (no fp16 emit)
    aggregate_kernel<<<AGG_NB, 1024, 0, stream>>>(hpre, g16, rowptr, me, tab, outp);
    mlp2_kernel<<<(Nn + 63) / 64, 256, 0, stream>>>(outp, W10, b10, W11, b11, outp, (__half*)nullptr);
}

// Round 14
// 196.533 us; speedup vs baseline: 1.4858x; 1.2621x over previous
//
#include <hip/hip_runtime.h>
#include <hip/hip_fp16.h>
#include <math.h>

#define Nn 50000
#define Ee 800000
#define Cc 96

// bucketed CSR-fill geometry
#define NPB 196                                 // nodes per bucket
#define NBK 256                                 // buckets (256*196 >= 50000)
#define P2_T 512
#define P2_E 4
#define P2_BLK (P2_T * P2_E)                    // 2048 edges/block
#define NB2 ((Ee + P2_BLK - 1) / P2_BLK)        // 391 blocks

typedef __attribute__((ext_vector_type(8))) __bf16 bf16x8;
typedef __attribute__((ext_vector_type(4))) float f32x4;

// split fp32 into hi/lo bf16 (truncation; lo captures next 8 mantissa bits)
__device__ inline void split_bf16(float v, unsigned short& hi, unsigned short& lo) {
    unsigned u = __float_as_uint(v);
    hi = (unsigned short)(u >> 16);
    float rem = v - __uint_as_float(((unsigned)hi) << 16);
    lo = (unsigned short)(__float_as_uint(rem) >> 16);
}

__device__ inline bool edge_valid(int s, int d) {
    return (unsigned)s < (unsigned)Nn && (unsigned)d < (unsigned)Nn;
}

// ============ table build (sort fused in; each block redoes the tiny sort) ============
// e(ea) = relu(ea*w0+b0) @ W_l1 + b_l1 is piecewise-linear in scalar ea with 96
// breakpoints; pattern k = #{t_i < ea}. tab[k][j] = float4{A[2j],B[2j],A[2j+1],B[2j+1]}.
__global__ __launch_bounds__(128) void build_table_kernel(
        const float* __restrict__ Wl0, const float* __restrict__ bl0,
        const float* __restrict__ Wl1, const float* __restrict__ bl1,
        float* __restrict__ st, float* __restrict__ tabf) {
    __shared__ float rt[Cc], rw[Cc], rb[Cc];
    __shared__ float sst[Cc], ssw[Cc], ssb[Cc];
    __shared__ int sso[Cc];
    int c = threadIdx.x;
    if (c < Cc) {
        float w = Wl0[c], b = bl0[c];
        rt[c] = (w != 0.0f) ? (-b / w) : INFINITY;
        rw[c] = w; rb[c] = b;
    }
    __syncthreads();
    if (c < Cc) {
        float t = rt[c];
        int r = 0;
        for (int jj = 0; jj < Cc; ++jj) {
            float tj = rt[jj];
            r += (tj < t || (tj == t && jj < c)) ? 1 : 0;  // stable rank sort
        }
        sst[r] = t; ssw[r] = rw[c]; ssb[r] = rb[c]; sso[r] = c;
    }
    __syncthreads();
    if (blockIdx.x == 0 && c < Cc) st[c] = sst[c];
    int k = blockIdx.x;          // 0..96
    if (c < Cc) {
        float a = 0.f, bacc = bl1[c];
        for (int i = 0; i < Cc; ++i) {
            float w = ssw[i], b = ssb[i];
            float wv = Wl1[sso[i] * Cc + c];
            bool act = (w > 0.f) ? (i < k) : ((w < 0.f) ? (i >= k) : (b > 0.f));
            if (act) { a = fmaf(w, wv, a); bacc = fmaf(b, wv, bacc); }
        }
        int base = k * (2 * Cc) + (c >> 1) * 4 + ((c & 1) << 1);
        tabf[base] = a;
        tabf[base + 1] = bacc;
    }
}

// ============ one-time weight hi/lo split (transposed) for mlp2 ============
// wsp layout: [mat][ {hi,lo} ][n][k], 4 mats x 2 x 96 x 96 shorts.
__global__ __launch_bounds__(96) void wsplit_kernel(
        const float* __restrict__ W0, const float* __restrict__ W1,
        const float* __restrict__ W2, const float* __restrict__ W3,
        unsigned short* __restrict__ wsp) {
    int mat = blockIdx.x / 96, n = blockIdx.x % 96, k = threadIdx.x;
    const float* W = (mat == 0) ? W0 : (mat == 1) ? W1 : (mat == 2) ? W2 : W3;
    float v = W[k * 96 + n];
    unsigned short hi, lo;
    split_bf16(v, hi, lo);
    unsigned short* base = wsp + (size_t)mat * 2 * 9216;
    base[n * 96 + k] = hi;
    base[9216 + n * 96 + k] = lo;
}

// fp32 -> fp16 copy (vectorized), for the gather path
__global__ __launch_bounds__(256) void cvt16_kernel(const float* __restrict__ in,
                                                    __half* __restrict__ out) {
    const int n4 = Nn * Cc / 4;   // 1.2M
    for (int i = blockIdx.x * blockDim.x + threadIdx.x; i < n4; i += gridDim.x * blockDim.x) {
        float4 v = ((const float4*)in)[i];
        ((__half2*)out)[2 * i] = __floats2half2_rn(v.x, v.y);
        ((__half2*)out)[2 * i + 1] = __floats2half2_rn(v.z, v.w);
    }
}

// ============ bucketed CSR fill (also produces rowptr — no separate hist/scan) ============
// phase 1: per-(block,bucket) histogram -> bmat[NB2][NBK]
__global__ __launch_bounds__(P2_T) void bucket_hist_kernel(const int* __restrict__ ei,
                                                           int* __restrict__ bmat) {
    __shared__ int cnt[NBK];
    int tid = threadIdx.x;
    for (int i = tid; i < NBK; i += P2_T) cnt[i] = 0;
    __syncthreads();
    int base = blockIdx.x * P2_BLK;
    for (int t = 0; t < P2_E; ++t) {
        int e = base + tid + t * P2_T;
        if (e < Ee) {
            int s = ei[e], d = ei[Ee + e];
            if (edge_valid(s, d)) atomicAdd(&cnt[d / NPB], 1);
        }
    }
    __syncthreads();
    for (int i = tid; i < NBK; i += P2_T) bmat[blockIdx.x * NBK + i] = cnt[i];
}

// phase 2: per-bucket scan over blocks -> relative offsets + bucket totals
__global__ __launch_bounds__(512) void bmat_scan_kernel(const int* __restrict__ bmat,
                                                        int* __restrict__ boffrel,
                                                        int* __restrict__ btot) {
    __shared__ int lds[512];
    int bk = blockIdx.x, t = threadIdx.x;
    int v = (t < NB2) ? bmat[t * NBK + bk] : 0;
    lds[t] = v;
    __syncthreads();
    for (int o = 1; o < 512; o <<= 1) {
        int u = (t >= o) ? lds[t - o] : 0;
        __syncthreads();
        lds[t] += u;
        __syncthreads();
    }
    if (t < NB2) boffrel[t * NBK + bk] = lds[t] - v;
    if (t == 511) btot[bk] = lds[511];
}

// phase 3: exclusive scan of bucket totals -> bucket base offsets
__global__ __launch_bounds__(256) void btot_scan_kernel(const int* __restrict__ btot,
                                                        int* __restrict__ bbase) {
    __shared__ int lds[256];
    int t = threadIdx.x;
    int v = btot[t];
    lds[t] = v;
    __syncthreads();
    for (int o = 1; o < 256; o <<= 1) {
        int u = (t >= o) ? lds[t - o] : 0;
        __syncthreads();
        lds[t] += u;
        __syncthreads();
    }
    bbase[t] = lds[t] - v;
}

// phase 4: scatter edges into bucket-segmented stage[] (block-contiguous runs).
// stage entry: { src | dlocal<<16 , bits(ea) }
__global__ __launch_bounds__(P2_T) void pass2_kernel(const int* __restrict__ ei,
                                                     const float* __restrict__ eattr,
                                                     const int* __restrict__ boffrel,
                                                     const int* __restrict__ bbase,
                                                     int2* __restrict__ stage) {
    __shared__ int curs[NBK];
    int tid = threadIdx.x;
    for (int i = tid; i < NBK; i += P2_T)
        curs[i] = bbase[i] + boffrel[blockIdx.x * NBK + i];
    __syncthreads();
    int base = blockIdx.x * P2_BLK;
    for (int t = 0; t < P2_E; ++t) {
        int e = base + tid + t * P2_T;
        if (e >= Ee) continue;
        int s = ei[e], d = ei[Ee + e];
        if (!edge_valid(s, d)) continue;
        int bk = d / NPB, dl = d - bk * NPB;
        int pos = atomicAdd(&curs[bk], 1);
        stage[pos] = make_int2(s | (dl << 16), __float_as_int(eattr[e]));
    }
}

// phase 5: per-bucket fine placement + rowptr. One block owns one bucket's
// me-region, so scattered me writes per region come from ONE CU (no write
// amplification). me entry: { src*192 | k<<24 , bits(ea) } (byte offset into
// the fp16 feature array premultiplied; 24+7 bits).
__global__ __launch_bounds__(512) void pass3_kernel(const int2* __restrict__ stage,
                                                    const int* __restrict__ bbase,
                                                    const int* __restrict__ btot,
                                                    const float* __restrict__ st,
                                                    int* __restrict__ rowptr,
                                                    int2* __restrict__ me) {
    __shared__ int cnt[NPB];
    __shared__ int scn[256];
    __shared__ int curs[NPB];
    __shared__ float ts[Cc];
    int bk = blockIdx.x, tid = threadIdx.x;
    if (tid < Cc) ts[tid] = st[tid];
    for (int i = tid; i < NPB; i += 512) cnt[i] = 0;
    __syncthreads();
    int seg0 = bbase[bk], segn = btot[bk];
    for (int p = tid; p < segn; p += 512)
        atomicAdd(&cnt[(stage[seg0 + p].x >> 16) & 0xFF], 1);
    __syncthreads();
    if (tid < 256) scn[tid] = (tid < NPB) ? cnt[tid] : 0;
    __syncthreads();
    for (int o = 1; o < 256; o <<= 1) {
        int u = (tid < 256 && tid >= o) ? scn[tid - o] : 0;
        __syncthreads();
        if (tid < 256) scn[tid] += u;
        __syncthreads();
    }
    int nstart = bk * NPB;
    if (tid < NPB) {
        int node = nstart + tid;
        if (node < Nn) {
            int e0 = seg0 + scn[tid] - cnt[tid];   // exclusive prefix
            rowptr[node] = e0;
            curs[tid] = e0;
        }
    }
    if (bk == NBK - 1 && tid == 0) rowptr[Nn] = seg0 + segn;
    __syncthreads();
    for (int p = tid; p < segn; p += 512) {
        int2 sv = stage[seg0 + p];
        unsigned sx = (unsigned)sv.x;
        int src = sx & 0xFFFF;
        int dl = (sx >> 16) & 0xFF;
        float ea = __int_as_float(sv.y);
        int lo = 0, hi = Cc;
        while (lo < hi) { int m = (lo + hi) >> 1; if (ts[m] < ea) lo = m + 1; else hi = m; }
        int pos = atomicAdd(&curs[dl], 1);
        me[pos] = make_int2((int)((unsigned)(src * 192) | ((unsigned)lo << 24)), sv.y);
    }
}

// ============ aggregation: out[n] = feat[n] + sum_in relu(feat[src] + e) ============
// Persistent blocks, table in LDS; neighbor gather from fp16 copy (premultiplied
// byte offsets in me). Lanes 0..47 own a channel PAIR.
#define AGG_NB 512
__global__ __launch_bounds__(1024) void aggregate_kernel(
        const float* __restrict__ feat, const __half* __restrict__ feat16,
        const int* __restrict__ rowptr, const int2* __restrict__ me,
        const float4* __restrict__ tab, float* __restrict__ out) {
    __shared__ float4 tl[(Cc + 1) * 48];   // 74496 B
    int tid = threadIdx.x;
    for (int i = tid; i < (Cc + 1) * 48; i += 1024) tl[i] = tab[i];
    __syncthreads();
    int wave = tid >> 6, lane = tid & 63;
    if (lane >= 48) return;               // no further syncs below
    int j = lane;
    const float2* f2 = (const float2*)feat;
    const char* gb = (const char*)feat16;
    int j4 = j << 2;
    for (int node = blockIdx.x * 16 + wave; node < Nn; node += AGG_NB * 16) {
        float2 acc = f2[(size_t)node * 48 + j];   // exact fp32 self-term
        int s = rowptr[node], e = rowptr[node + 1];
        int p = s;
        for (; p + 4 <= e; p += 4) {
            int2 m0 = me[p], m1 = me[p + 1], m2 = me[p + 2], m3 = me[p + 3];
            unsigned x0 = (unsigned)m0.x, x1 = (unsigned)m1.x;
            unsigned x2 = (unsigned)m2.x, x3 = (unsigned)m3.x;
            __half2 h0 = *(const __half2*)(gb + (x0 & 0xFFFFFF) + j4);
            __half2 h1 = *(const __half2*)(gb + (x1 & 0xFFFFFF) + j4);
            __half2 h2 = *(const __half2*)(gb + (x2 & 0xFFFFFF) + j4);
            __half2 h3 = *(const __half2*)(gb + (x3 & 0xFFFFFF) + j4);
            float4 t0 = tl[(x0 >> 24) * 48 + j];
            float4 t1 = tl[(x1 >> 24) * 48 + j];
            float4 t2 = tl[(x2 >> 24) * 48 + j];
            float4 t3 = tl[(x3 >> 24) * 48 + j];
            float2 f0 = __half22float2(h0), f1 = __half22float2(h1);
            float2 fb2 = __half22float2(h2), f3 = __half22float2(h3);
            float ea0 = __int_as_float(m0.y), ea1 = __int_as_float(m1.y);
            float ea2 = __int_as_float(m2.y), ea3 = __int_as_float(m3.y);
            acc.x += fmaxf(f0.x + fmaf(ea0, t0.x, t0.y), 0.f);
            acc.y += fmaxf(f0.y + fmaf(ea0, t0.z, t0.w), 0.f);
            acc.x += fmaxf(f1.x + fmaf(ea1, t1.x, t1.y), 0.f);
            acc.y += fmaxf(f1.y + fmaf(ea1, t1.z, t1.w), 0.f);
            acc.x += fmaxf(fb2.x + fmaf(ea2, t2.x, t2.y), 0.f);
            acc.y += fmaxf(fb2.y + fmaf(ea2, t2.z, t2.w), 0.f);
            acc.x += fmaxf(f3.x + fmaf(ea3, t3.x, t3.y), 0.f);
            acc.y += fmaxf(f3.y + fmaf(ea3, t3.z, t3.w), 0.f);
        }
        for (; p < e; ++p) {
            int2 m0 = me[p];
            unsigned x0 = (unsigned)m0.x;
            float2 f0 = __half22float2(*(const __half2*)(gb + (x0 & 0xFFFFFF) + j4));
            float4 t0 = tl[(x0 >> 24) * 48 + j];
            float ea0 = __int_as_float(m0.y);
            acc.x += fmaxf(f0.x + fmaf(ea0, t0.x, t0.y), 0.f);
            acc.y += fmaxf(f0.y + fmaf(ea0, t0.z, t0.w), 0.f);
        }
        ((float2*)out)[(size_t)node * 48 + j] = acc;
    }
}

// ============ fused 2-layer node MLP via bf16x3 MFMA ============
// Weights pre-split (wsp); staging is pure 16B copies. IN-PLACE SAFE.
#define MLP_PAD 104
__global__ __launch_bounds__(256) void mlp2_kernel(
        const float* __restrict__ in,
        const unsigned short* __restrict__ wh1, const unsigned short* __restrict__ wl1,
        const float* __restrict__ b1g,
        const unsigned short* __restrict__ wh2, const unsigned short* __restrict__ wl2,
        const float* __restrict__ b2g, float* __restrict__ out,
        __half* __restrict__ out16) {
    __shared__ __attribute__((aligned(16))) unsigned short xh[64 * MLP_PAD], xl[64 * MLP_PAD];
    __shared__ __attribute__((aligned(16))) unsigned short wth[96 * MLP_PAD], wtl[96 * MLP_PAD];
    __shared__ float bb1[Cc], bb2[Cc];
    int tid = threadIdx.x;
    int row0 = blockIdx.x * 64;

    for (int t = 0; t < 24; ++t) {
        int idx = tid + t * 256;                 // 0..6143
        int r = idx / Cc, c = idx - r * Cc;
        int gr = row0 + r;
        float v = (gr < Nn) ? in[(size_t)gr * Cc + c] : 0.f;
        unsigned short hi, lo;
        split_bf16(v, hi, lo);
        xh[r * MLP_PAD + c] = hi; xl[r * MLP_PAD + c] = lo;
    }
    // stage pre-split W1 (16B copies; rows 192B in global, 208B in LDS — both 16B aligned)
    for (int i = tid; i < 1152; i += 256) {
        int n = i / 12, kc = (i % 12) * 8;
        *(uint4*)&wth[n * MLP_PAD + kc] = *(const uint4*)&wh1[n * 96 + kc];
        *(uint4*)&wtl[n * MLP_PAD + kc] = *(const uint4*)&wl1[n * 96 + kc];
    }
    if (tid < Cc) { bb1[tid] = b1g[tid]; bb2[tid] = b2g[tid]; }
    __syncthreads();

    int lane = tid & 63, w = tid >> 6;
    int li = lane & 15, lg = lane >> 4;
    int arow = w * 16 + li;

    f32x4 acc[6];
    // ---- layer 1 ----
    for (int nt = 0; nt < 6; ++nt) {
        float bv = bb1[nt * 16 + li];
        acc[nt] = (f32x4){bv, bv, bv, bv};
    }
    for (int k0 = 0; k0 < Cc; k0 += 32) {
        int ko = k0 + lg * 8;
        bf16x8 ah = *(const bf16x8*)&xh[arow * MLP_PAD + ko];
        bf16x8 al = *(const bf16x8*)&xl[arow * MLP_PAD + ko];
        for (int nt = 0; nt < 6; ++nt) {
            bf16x8 bh = *(const bf16x8*)&wth[(nt * 16 + li) * MLP_PAD + ko];
            bf16x8 bl = *(const bf16x8*)&wtl[(nt * 16 + li) * MLP_PAD + ko];
            acc[nt] = __builtin_amdgcn_mfma_f32_16x16x32_bf16(ah, bh, acc[nt], 0, 0, 0);
            acc[nt] = __builtin_amdgcn_mfma_f32_16x16x32_bf16(ah, bl, acc[nt], 0, 0, 0);
            acc[nt] = __builtin_amdgcn_mfma_f32_16x16x32_bf16(al, bh, acc[nt], 0, 0, 0);
        }
    }
    __syncthreads();   // all waves done reading wt & x
    for (int nt = 0; nt < 6; ++nt) {
        for (int r = 0; r < 4; ++r) {
            float v = fmaxf(acc[nt][r], 0.f);
            int row = w * 16 + lg * 4 + r;
            int col = nt * 16 + li;
            unsigned short hi, lo;
            split_bf16(v, hi, lo);
            xh[row * MLP_PAD + col] = hi; xl[row * MLP_PAD + col] = lo;
        }
    }
    for (int i = tid; i < 1152; i += 256) {
        int n = i / 12, kc = (i % 12) * 8;
        *(uint4*)&wth[n * MLP_PAD + kc] = *(const uint4*)&wh2[n * 96 + kc];
        *(uint4*)&wtl[n * MLP_PAD + kc] = *(const uint4*)&wl2[n * 96 + kc];
    }
    __syncthreads();

    // ---- layer 2 ----
    for (int nt = 0; nt < 6; ++nt) {
        float bv = bb2[nt * 16 + li];
        acc[nt] = (f32x4){bv, bv, bv, bv};
    }
    for (int k0 = 0; k0 < Cc; k0 += 32) {
        int ko = k0 + lg * 8;
        bf16x8 ah = *(const bf16x8*)&xh[arow * MLP_PAD + ko];
        bf16x8 al = *(const bf16x8*)&xl[arow * MLP_PAD + ko];
        for (int nt = 0; nt < 6; ++nt) {
            bf16x8 bh = *(const bf16x8*)&wth[(nt * 16 + li) * MLP_PAD + ko];
            bf16x8 bl = *(const bf16x8*)&wtl[(nt * 16 + li) * MLP_PAD + ko];
            acc[nt] = __builtin_amdgcn_mfma_f32_16x16x32_bf16(ah, bh, acc[nt], 0, 0, 0);
            acc[nt] = __builtin_amdgcn_mfma_f32_16x16x32_bf16(ah, bl, acc[nt], 0, 0, 0);
            acc[nt] = __builtin_amdgcn_mfma_f32_16x16x32_bf16(al, bh, acc[nt], 0, 0, 0);
        }
    }
    for (int nt = 0; nt < 6; ++nt) {
        for (int r = 0; r < 4; ++r) {
            int grow = row0 + w * 16 + lg * 4 + r;
            if (grow < Nn) {
                float v = fmaxf(acc[nt][r], 0.f);
                out[(size_t)grow * Cc + nt * 16 + li] = v;
                if (out16) out16[(size_t)grow * Cc + nt * 16 + li] = __float2half_rn(v);
            }
        }
    }
}

extern "C" void kernel_launch(void* const* d_in, const int* in_sizes, int n_in,
                              void* d_out, int out_size, void* d_ws, size_t ws_size,
                              hipStream_t stream) {
    const float* x     = (const float*)d_in[0];
    const int*   ei    = (const int*)d_in[1];     // int64 in ref -> int32 from harness
    const float* eattr = (const float*)d_in[2];
    const float* Wl0   = (const float*)d_in[3];
    const float* bl0   = (const float*)d_in[4];
    const float* Wl1   = (const float*)d_in[5];
    const float* bl1   = (const float*)d_in[6];
    const float* W00   = (const float*)d_in[7];
    const float* b00   = (const float*)d_in[8];
    const float* W01   = (const float*)d_in[9];
    const float* b01   = (const float*)d_in[10];
    const float* W10   = (const float*)d_in[11];
    const float* b10   = (const float*)d_in[12];
    const float* W11   = (const float*)d_in[13];
    const float* b11   = (const float*)d_in[14];
    float* outp = (float*)d_out;

    // workspace carve-up (~37 MB), 256B-aligned
    char* w = (char*)d_ws;
    size_t off = 0;
    auto alloc = [&](size_t bytes) { size_t r = off; off += (bytes + 255) & ~(size_t)255; return r; };
    int*   rowptr  = (int*)  (w + alloc((size_t)(Nn + 1) * 4));
    int2*  me      = (int2*) (w + alloc((size_t)Ee * 8));
    float* st      = (float*)(w + alloc((size_t)Cc * 4));
    int*   bmat    = (int*)  (w + alloc((size_t)NB2 * NBK * 4));
    int*   boffrel = (int*)  (w + alloc((size_t)NB2 * NBK * 4));
    int*   btot    = (int*)  (w + alloc((size_t)NBK * 4));
    int*   bbase   = (int*)  (w + alloc((size_t)NBK * 4));
    float* tabf    = (float*)(w + alloc((size_t)(Cc + 1) * 2 * Cc * 4));
    unsigned short* wsp = (unsigned short*)(w + alloc((size_t)4 * 2 * 9216 * 2));
    float* hpre    = (float*)(w + alloc((size_t)Nn * Cc * 4));
    __half* g16    = (__half*)(w + alloc((size_t)Nn * Cc * 2));
    int2*  stage   = (int2*)hpre;   // staging aliases hpre (dead until aggregate)
    (void)ws_size; (void)in_sizes; (void)n_in; (void)out_size;

    build_table_kernel<<<Cc + 1, 128, 0, stream>>>(Wl0, bl0, Wl1, bl1, st, tabf);
    wsplit_kernel<<<384, 96, 0, stream>>>(W00, W01, W10, W11, wsp);
    bucket_hist_kernel<<<NB2, P2_T, 0, stream>>>(ei, bmat);
    bmat_scan_kernel<<<NBK, 512, 0, stream>>>(bmat, boffrel, btot);
    btot_scan_kernel<<<1, 256, 0, stream>>>(btot, bbase);
    pass2_kernel<<<NB2, P2_T, 0, stream>>>(ei, eattr, boffrel, bbase, stage);
    pass3_kernel<<<NBK, 512, 0, stream>>>(stage, bbase, btot, st, rowptr, me);
    cvt16_kernel<<<1024, 256, 0, stream>>>(x, g16);

    const float4* tab = (const float4*)tabf;
    const unsigned short* wh00 = wsp;                 // [mat][hi/lo][96][96]
    const unsigned short* wl00 = wsp + 9216;
    const unsigned short* wh01 = wsp + 18432;
    const unsigned short* wl01 = wsp + 27648;
    const unsigned short* wh10 = wsp + 36864;
    const unsigned short* wl10 = wsp + 46080;
    const unsigned short* wh11 = wsp + 55296;
    const unsigned short* wl11 = wsp + 64512;

    // conv 1: agg(x, x16) -> hpre; mlp in-place on hpre, also emits h16 into g16
    aggregate_kernel<<<AGG_NB, 1024, 0, stream>>>(x, g16, rowptr, me, tab, hpre);
    mlp2_kernel<<<(Nn + 63) / 64, 256, 0, stream>>>(hpre, wh00, wl00, b00, wh01, wl01, b01, hpre, g16);
    // conv 2: agg(h, h16) -> d_out; final mlp in-place on d_out (no fp16 emit)
    aggregate_kernel<<<AGG_NB, 1024, 0, stream>>>(hpre, g16, rowptr, me, tab, outp);
    mlp2_kernel<<<(Nn + 63) / 64, 256, 0, stream>>>(outp, wh10, wl10, b10, wh11, wl11, b11, outp, (__half*)nullptr);
}